// Round 4
// baseline (430.209 us; speedup 1.0000x reference)
//
#include <hip/hip_runtime.h>

#define NODES 50000
#define EDGES 800000
#define HID   128
#define HEADS 4
// DK = 32, scale = 1/sqrt(32)
#define SCORE_SCALE 0.17677669529663687f

typedef unsigned int       u32;
typedef unsigned short     u16;
typedef unsigned long long u64;

typedef __attribute__((ext_vector_type(8))) short bf16x8;
typedef __attribute__((ext_vector_type(4))) float f32x4;

// round-to-nearest-even f32 -> bf16
__device__ __forceinline__ u16 f2bf(float f) {
    u32 u = __builtin_bit_cast(u32, f);
    return (u16)((u + 0x7FFFu + ((u >> 16) & 1u)) >> 16);
}
__device__ __forceinline__ float bflo(u32 u) { return __builtin_bit_cast(float, u << 16); }
__device__ __forceinline__ float bfhi(u32 u) { return __builtin_bit_cast(float, u & 0xFFFF0000u); }
__device__ __forceinline__ float bdot2(u32 a, u32 b) {
    return bflo(a) * bflo(b) + bfhi(a) * bfhi(b);
}

// ---------------------------------------------------------------------------
// W prep: Wt[n][k] = bf16(W[k][n]), both 128x128. 2 matrices.
// ---------------------------------------------------------------------------
__global__ __launch_bounds__(256) void wprep(
    const float* __restrict__ Wq, const float* __restrict__ Wk,
    u16* __restrict__ Wqt, u16* __restrict__ Wkt)
{
    int e   = blockIdx.x * 256 + threadIdx.x;
    int mat = e >> 14;
    int idx = e & 16383;
    int k  = idx >> 7;
    int nn = idx & 127;
    const float* W = mat ? Wk : Wq;
    u16*        Wt = mat ? Wkt : Wqt;
    Wt[nn * 128 + k] = f2bf(W[idx]);
}

// ---------------------------------------------------------------------------
// MFMA Q/K projection. Wave = one 16-row tile, both matrices.
// xb copy emitted QUARTER-MAJOR: xb[(ks*N + row)*32 + d]
// ---------------------------------------------------------------------------
__global__ __launch_bounds__(256) void gemm_qk_mfma(
    const float* __restrict__ x,
    const u16* __restrict__ Wqt, const float* __restrict__ bq,
    const u16* __restrict__ Wkt, const float* __restrict__ bk,
    u16* __restrict__ qb, u16* __restrict__ kb, u16* __restrict__ xb, int n)
{
    const int l  = threadIdx.x & 63;
    const int w  = threadIdx.x >> 6;
    const int lr = l & 15;
    const int kg = l >> 4;

    const int arow   = blockIdx.x * 64 + w * 16 + lr;
    const bool av    = (arow < n);
    const int  arowc = av ? arow : (n - 1);

    bf16x8 afrag[4];
    #pragma unroll
    for (int ks = 0; ks < 4; ++ks) {
        const float* px = x + (size_t)arowc * HID + ks * 32 + kg * 8;
        float4 p0 = *(const float4*)px;
        float4 p1 = *(const float4*)(px + 4);
        uint4 pk;
        pk.x = (u32)f2bf(p0.x) | ((u32)f2bf(p0.y) << 16);
        pk.y = (u32)f2bf(p0.z) | ((u32)f2bf(p0.w) << 16);
        pk.z = (u32)f2bf(p1.x) | ((u32)f2bf(p1.y) << 16);
        pk.w = (u32)f2bf(p1.z) | ((u32)f2bf(p1.w) << 16);
        afrag[ks] = __builtin_bit_cast(bf16x8, pk);
        if (av) *(uint4*)(xb + ((size_t)ks * n + arow) * 32 + kg * 8) = pk;
    }

    #pragma unroll
    for (int mat = 0; mat < 2; ++mat) {
        const u16*   Wt   = mat ? Wkt : Wqt;
        const float* bias = mat ? bk : bq;
        u16*         outp = mat ? kb : qb;

        #pragma unroll
        for (int cb = 0; cb < 8; ++cb) {
            float bc = bias[cb * 16 + lr];
            f32x4 acc = {bc, bc, bc, bc};
            #pragma unroll
            for (int ks = 0; ks < 4; ++ks) {
                bf16x8 bfrag = __builtin_bit_cast(bf16x8,
                    *(const uint4*)(Wt + (size_t)(cb * 16 + lr) * 128 + ks * 32 + kg * 8));
                acc = __builtin_amdgcn_mfma_f32_16x16x32_bf16(afrag[ks], bfrag, acc, 0, 0, 0);
            }
            #pragma unroll
            for (int reg = 0; reg < 4; ++reg) {
                int gr = blockIdx.x * 64 + w * 16 + kg * 4 + reg;
                if (gr < n) outp[(size_t)gr * HID + cb * 16 + lr] = f2bf(acc[reg]);
            }
        }
    }
}

// ---------------------------------------------------------------------------
// per-edge scores (bf16 q/k) -> exp -> evals, atomic sums into nsum.
// Also folds the src-degree histogram (lane 0 of each 16-group).
// ---------------------------------------------------------------------------
__global__ __launch_bounds__(256) void score_kernel(
    const u16* __restrict__ qb, const u16* __restrict__ kb,
    const int* __restrict__ ei,
    float* __restrict__ evals, float* __restrict__ nsum, int* __restrict__ deg)
{
    const int t    = threadIdx.x;
    const int l16  = t & 15;
    const int edge = blockIdx.x * 16 + (t >> 4);

    const int src = ei[edge];
    const int dst = ei[EDGES + edge];

    uint4 qv = *(const uint4*)(qb + (size_t)src * HID + l16 * 8);
    uint4 kv = *(const uint4*)(kb + (size_t)dst * HID + l16 * 8);
    float p = bdot2(qv.x, kv.x) + bdot2(qv.y, kv.y) +
              bdot2(qv.z, kv.z) + bdot2(qv.w, kv.w);

    p += __shfl_xor(p, 1);
    p += __shfl_xor(p, 2);

    if (l16 == 0) atomicAdd(&deg[src], 1);
    if ((l16 & 3) == 0) {
        int head = l16 >> 2;
        float e = __expf(p * SCORE_SCALE);
        evals[(size_t)edge * HEADS + head] = e;
        atomicAdd(&nsum[(size_t)dst * HEADS + head], e);
    }
}

// ---------------------------------------------------------------------------
// two-level exclusive scan of deg -> off (+cursor)
// ---------------------------------------------------------------------------
__global__ __launch_bounds__(1024) void scan1(
    const int* __restrict__ deg, int* __restrict__ off,
    int* __restrict__ part, int n)
{
    __shared__ int sd[1024];
    int t = threadIdx.x, i = blockIdx.x * 1024 + t;
    int v = (i < n) ? deg[i] : 0;
    sd[t] = v;
    __syncthreads();
    #pragma unroll
    for (int o = 1; o < 1024; o <<= 1) {
        int a = (t >= o) ? sd[t - o] : 0;
        __syncthreads();
        sd[t] += a;
        __syncthreads();
    }
    if (i < n) off[i] = sd[t] - v;
    if (t == 1023) part[blockIdx.x] = sd[1023];
}

__global__ __launch_bounds__(64) void scan2(int* __restrict__ part,
                                            int* __restrict__ off_n, int nb)
{
    int t = threadIdx.x;
    int v = (t < nb) ? part[t] : 0;
    int orig = v;
    #pragma unroll
    for (int o = 1; o < 64; o <<= 1) {
        int a = __shfl_up(v, o);
        if (t >= o) v += a;
    }
    if (t < nb) part[t] = v - orig;
    if (t == 63) *off_n = v;
}

__global__ __launch_bounds__(1024) void scan3(
    int* __restrict__ off, int* __restrict__ cur,
    const int* __restrict__ part, int n)
{
    int i = blockIdx.x * 1024 + threadIdx.x;
    if (i < n) {
        int o = off[i] + part[blockIdx.x];
        off[i] = o;
        cur[i] = o;
    }
}

// ---------------------------------------------------------------------------
// head-mean attention + packed CSR fill: epack = dst(16b) | bf16(att)(16b)
// ---------------------------------------------------------------------------
__global__ __launch_bounds__(256) void finalize_kernel(
    const int* __restrict__ ei,
    const float* __restrict__ evals, const float* __restrict__ nsum,
    int* __restrict__ cur, u32* __restrict__ epack)
{
    int e = blockIdx.x * 256 + threadIdx.x;
    if (e >= EDGES) return;
    int src = ei[e];
    int dst = ei[EDGES + e];
    float4 ev = *(const float4*)(evals + (size_t)e * HEADS);
    float4 sv = *(const float4*)(nsum  + (size_t)dst * HEADS);
    float am = 0.25f * (ev.x / (sv.x + 1e-16f) + ev.y / (sv.y + 1e-16f) +
                        ev.z / (sv.z + 1e-16f) + ev.w / (sv.w + 1e-16f));
    int pos = atomicAdd(&cur[src], 1);
    epack[pos] = (u32)dst | ((u32)f2bf(am) << 16);
}

// ---------------------------------------------------------------------------
// Phased Euler step. bf16 state is QUARTER-MAJOR: one row-quarter = 64 B line.
// Persistent grid (2048 blocks, all resident); internal phase loop q=0..3 so
// the live gather window is one 3.2 MB quarter slice -> fits per-XCD L2.
// 16-lane group per node; streaming traffic is non-temporal.
// ---------------------------------------------------------------------------
template<int WRITE_BF>
__global__ __launch_bounds__(256, 8) void spmv_phased(
    const float* __restrict__ inf, const u16* __restrict__ inb,
    float* __restrict__ outf, u16* __restrict__ outb,
    const int* __restrict__ off, const u32* __restrict__ epack, int n)
{
    const int tid  = threadIdx.x;
    const int l16  = tid & 15;
    const int grpb = tid & 48;                       // group base within wave
    const int grp  = (tid >> 4) & 3;                 // group index in wave
    const int gw   = blockIdx.x * 4 + (tid >> 6);    // global wave id
    const int NW   = gridDim.x * 4;

    const int n0 = (int)((long long)gw       * n / NW);
    const int n1 = (int)((long long)(gw + 1) * n / NW);

    for (int q = 0; q < 4; ++q) {
        const u32* inq = (const u32*)(inb + (size_t)q * n * 32);

        for (int nb = n0; nb < n1; nb += 4) {
            const int w   = nb + grp;
            const bool act = (w < n1);
            int beg = 0, end = 0;
            if (act) { beg = off[w]; end = off[w + 1]; }

            float ax = 0.f, ay = 0.f;
            for (int j = beg; j < end; j += 16) {
                int cnt = end - j; if (cnt > 16) cnt = 16;
                u32 e = 0;
                if (l16 < cnt) e = __builtin_nontemporal_load(epack + j + l16);

                int jj = 0;
                for (; jj + 8 <= cnt; jj += 8) {
                    u32 ee[8], s[8];
                    #pragma unroll
                    for (int u = 0; u < 8; ++u) ee[u] = __shfl(e, grpb + jj + u);
                    #pragma unroll
                    for (int u = 0; u < 8; ++u)
                        s[u] = inq[(size_t)(ee[u] & 0xFFFFu) * 16 + l16];
                    #pragma unroll
                    for (int u = 0; u < 8; ++u) {
                        float vv = bfhi(ee[u]);
                        ax += vv * bflo(s[u]);
                        ay += vv * bfhi(s[u]);
                    }
                }
                for (; jj + 4 <= cnt; jj += 4) {
                    u32 ee[4], s[4];
                    #pragma unroll
                    for (int u = 0; u < 4; ++u) ee[u] = __shfl(e, grpb + jj + u);
                    #pragma unroll
                    for (int u = 0; u < 4; ++u)
                        s[u] = inq[(size_t)(ee[u] & 0xFFFFu) * 16 + l16];
                    #pragma unroll
                    for (int u = 0; u < 4; ++u) {
                        float vv = bfhi(ee[u]);
                        ax += vv * bflo(s[u]);
                        ay += vv * bfhi(s[u]);
                    }
                }
                for (; jj < cnt; ++jj) {
                    u32 ee = __shfl(e, grpb + jj);
                    u32 s  = inq[(size_t)(ee & 0xFFFFu) * 16 + l16];
                    float vv = bfhi(ee);
                    ax += vv * bflo(s);
                    ay += vv * bfhi(s);
                }
            }

            if (act) {
                const size_t fo = (size_t)w * HID + q * 32 + l16 * 2;
                u64 xr = __builtin_nontemporal_load((const u64*)(inf + fo));
                float2 xi = __builtin_bit_cast(float2, xr);
                float2 o;
                o.x = 0.75f * xi.x + 0.25f * ax;
                o.y = 0.75f * xi.y + 0.25f * ay;
                __builtin_nontemporal_store(__builtin_bit_cast(u64, o), (u64*)(outf + fo));
                if (WRITE_BF) {
                    u32 pb = ((u32)f2bf(o.y) << 16) | (u32)f2bf(o.x);
                    __builtin_nontemporal_store(pb,
                        (u32*)(outb + ((size_t)q * n + w) * 32 + l16 * 2));
                }
            }
        }
    }
}

// ---------------------------------------------------------------------------
extern "C" void kernel_launch(void* const* d_in, const int* in_sizes, int n_in,
                              void* d_out, int out_size, void* d_ws, size_t ws_size,
                              hipStream_t stream)
{
    (void)in_sizes; (void)n_in; (void)out_size; (void)ws_size;

    const float* x  = (const float*)d_in[0];
    const float* Wq = (const float*)d_in[1];
    const float* bq = (const float*)d_in[2];
    const float* Wk = (const float*)d_in[3];
    const float* bk = (const float*)d_in[4];
    const int*   ei = (const int*)d_in[5];
    float* out = (float*)d_out;

    const int N = NODES, E = EDGES;
    const size_t ROWB_B = (size_t)N * HID * 2;   // 12.8 MB bf16 state

    char* ws = (char*)d_ws;
    // region A: qb|kb  -- dead after score -- reused as stA_f
    u16*   qb    = (u16*)(ws);
    u16*   kb    = (u16*)(ws + ROWB_B);
    float* stA_f = (float*)(ws);
    ws += 2 * ROWB_B;
    // region B: xb|evals -- dead after spmv1 / finalize -- reused as stB_f
    u16*   xb    = (u16*)(ws);
    float* evals = (float*)(ws + ROWB_B);
    float* stB_f = (float*)(xb);
    ws += 2 * ROWB_B;
    u16*   stA_b = (u16*)ws;  ws += ROWB_B;
    u16*   stB_b = (u16*)ws;  ws += ROWB_B;
    float* nsum  = (float*)ws; ws += (size_t)N * HEADS * 4;
    int*   deg   = (int*)ws;   ws += (size_t)N * 4;
    int*   off   = (int*)ws;   ws += ((size_t)(N + 1) * 4 + 255) & ~255ull;
    int*   cur   = (int*)ws;   ws += (size_t)N * 4;
    int*   part  = (int*)ws;   ws += 256;
    u32*   epack = (u32*)ws;   ws += (size_t)E * 4;
    u16*   Wqt   = (u16*)ws;   ws += (size_t)128 * 128 * 2;
    u16*   Wkt   = (u16*)ws;   ws += (size_t)128 * 128 * 2;

    // zero nsum + deg (contiguous)
    hipMemsetAsync(nsum, 0, (size_t)N * HEADS * 4 + (size_t)N * 4, stream);

    // W -> bf16 transposed
    wprep<<<128, 256, 0, stream>>>(Wq, Wk, Wqt, Wkt);

    // Q/K projections via MFMA (bf16 out) + quarter-major bf16 copy of x
    gemm_qk_mfma<<<(N + 63) / 64, 256, 0, stream>>>(
        x, Wqt, bq, Wkt, bk, qb, kb, xb, N);

    // per-edge scores -> exp -> segment sums (+deg histogram)
    score_kernel<<<E / 16, 256, 0, stream>>>(qb, kb, ei, evals, nsum, deg);

    // CSR offsets: two-level scan
    const int nb = (N + 1023) / 1024;
    scan1<<<nb, 1024, 0, stream>>>(deg, off, part, N);
    scan2<<<1, 64, 0, stream>>>(part, off + N, nb);
    scan3<<<nb, 1024, 0, stream>>>(off, cur, part, N);

    // attention mean + packed CSR fill
    finalize_kernel<<<E / 256, 256, 0, stream>>>(ei, evals, nsum, cur, epack);

    // 4 Euler steps (phased quarter-sliced gathers)
    spmv_phased<1><<<2048, 256, 0, stream>>>(x,     xb,    stA_f, stA_b, off, epack, N);
    spmv_phased<1><<<2048, 256, 0, stream>>>(stA_f, stA_b, stB_f, stB_b, off, epack, N);
    spmv_phased<1><<<2048, 256, 0, stream>>>(stB_f, stB_b, stA_f, stA_b, off, epack, N);
    spmv_phased<0><<<2048, 256, 0, stream>>>(stA_f, stA_b, out,   nullptr, off, epack, N);
}

// Round 5
// 330.759 us; speedup vs baseline: 1.3007x; 1.3007x over previous
//
#include <hip/hip_runtime.h>

#define NODES 50000
#define EDGES 800000
#define HID   128
#define HEADS 4
// DK = 32, scale = 1/sqrt(32)
#define SCORE_SCALE 0.17677669529663687f

typedef unsigned int       u32;
typedef unsigned short     u16;
typedef unsigned long long u64;

typedef __attribute__((ext_vector_type(8))) short bf16x8;
typedef __attribute__((ext_vector_type(4))) float f32x4;

// round-to-nearest-even f32 -> bf16
__device__ __forceinline__ u16 f2bf(float f) {
    u32 u = __builtin_bit_cast(u32, f);
    return (u16)((u + 0x7FFFu + ((u >> 16) & 1u)) >> 16);
}
__device__ __forceinline__ float bflo(u32 u) { return __builtin_bit_cast(float, u << 16); }
__device__ __forceinline__ float bfhi(u32 u) { return __builtin_bit_cast(float, u & 0xFFFF0000u); }
__device__ __forceinline__ float bdot2(u32 a, u32 b) {
    return bflo(a) * bflo(b) + bfhi(a) * bfhi(b);
}

// ---------------------------------------------------------------------------
// W prep: Wt[n][k] = bf16(W[k][n]), both 128x128. 2 matrices.
// ---------------------------------------------------------------------------
__global__ __launch_bounds__(256) void wprep(
    const float* __restrict__ Wq, const float* __restrict__ Wk,
    u16* __restrict__ Wqt, u16* __restrict__ Wkt)
{
    int e   = blockIdx.x * 256 + threadIdx.x;
    int mat = e >> 14;
    int idx = e & 16383;
    int k  = idx >> 7;
    int nn = idx & 127;
    const float* W = mat ? Wk : Wq;
    u16*        Wt = mat ? Wkt : Wqt;
    Wt[nn * 128 + k] = f2bf(W[idx]);
}

// ---------------------------------------------------------------------------
// MFMA Q/K projection. Wave = one 16-row tile, both matrices.
// Also emits row-major bf16 copy of x.
// ---------------------------------------------------------------------------
__global__ __launch_bounds__(256) void gemm_qk_mfma(
    const float* __restrict__ x,
    const u16* __restrict__ Wqt, const float* __restrict__ bq,
    const u16* __restrict__ Wkt, const float* __restrict__ bk,
    u16* __restrict__ qb, u16* __restrict__ kb, u16* __restrict__ xb, int n)
{
    const int l  = threadIdx.x & 63;
    const int w  = threadIdx.x >> 6;
    const int lr = l & 15;
    const int kg = l >> 4;

    const int arow   = blockIdx.x * 64 + w * 16 + lr;
    const bool av    = (arow < n);
    const int  arowc = av ? arow : (n - 1);

    bf16x8 afrag[4];
    #pragma unroll
    for (int ks = 0; ks < 4; ++ks) {
        const float* px = x + (size_t)arowc * HID + ks * 32 + kg * 8;
        float4 p0 = *(const float4*)px;
        float4 p1 = *(const float4*)(px + 4);
        uint4 pk;
        pk.x = (u32)f2bf(p0.x) | ((u32)f2bf(p0.y) << 16);
        pk.y = (u32)f2bf(p0.z) | ((u32)f2bf(p0.w) << 16);
        pk.z = (u32)f2bf(p1.x) | ((u32)f2bf(p1.y) << 16);
        pk.w = (u32)f2bf(p1.z) | ((u32)f2bf(p1.w) << 16);
        afrag[ks] = __builtin_bit_cast(bf16x8, pk);
        if (av) *(uint4*)(xb + (size_t)arow * HID + ks * 32 + kg * 8) = pk;
    }

    #pragma unroll
    for (int mat = 0; mat < 2; ++mat) {
        const u16*   Wt   = mat ? Wkt : Wqt;
        const float* bias = mat ? bk : bq;
        u16*         outp = mat ? kb : qb;

        #pragma unroll
        for (int cb = 0; cb < 8; ++cb) {
            float bc = bias[cb * 16 + lr];
            f32x4 acc = {bc, bc, bc, bc};
            #pragma unroll
            for (int ks = 0; ks < 4; ++ks) {
                bf16x8 bfrag = __builtin_bit_cast(bf16x8,
                    *(const uint4*)(Wt + (size_t)(cb * 16 + lr) * 128 + ks * 32 + kg * 8));
                acc = __builtin_amdgcn_mfma_f32_16x16x32_bf16(afrag[ks], bfrag, acc, 0, 0, 0);
            }
            #pragma unroll
            for (int reg = 0; reg < 4; ++reg) {
                int gr = blockIdx.x * 64 + w * 16 + kg * 4 + reg;
                if (gr < n) outp[(size_t)gr * HID + cb * 16 + lr] = f2bf(acc[reg]);
            }
        }
    }
}

// ---------------------------------------------------------------------------
// out-degree histogram over src (separate kernel -- folding it into score
// cost 30us in round 4 via TCC atomic contention)
// ---------------------------------------------------------------------------
__global__ __launch_bounds__(256) void hist_kernel(
    const int* __restrict__ ei, int* __restrict__ deg)
{
    int i = blockIdx.x * 256 + threadIdx.x;
    if (i < EDGES) atomicAdd(&deg[ei[i]], 1);
}

// ---------------------------------------------------------------------------
// two-level exclusive scan of deg -> off (+cursor)
// ---------------------------------------------------------------------------
__global__ __launch_bounds__(1024) void scan1(
    const int* __restrict__ deg, int* __restrict__ off,
    int* __restrict__ part, int n)
{
    __shared__ int sd[1024];
    int t = threadIdx.x, i = blockIdx.x * 1024 + t;
    int v = (i < n) ? deg[i] : 0;
    sd[t] = v;
    __syncthreads();
    #pragma unroll
    for (int o = 1; o < 1024; o <<= 1) {
        int a = (t >= o) ? sd[t - o] : 0;
        __syncthreads();
        sd[t] += a;
        __syncthreads();
    }
    if (i < n) off[i] = sd[t] - v;
    if (t == 1023) part[blockIdx.x] = sd[1023];
}

__global__ __launch_bounds__(64) void scan2(int* __restrict__ part,
                                            int* __restrict__ off_n, int nb)
{
    int t = threadIdx.x;
    int v = (t < nb) ? part[t] : 0;
    int orig = v;
    #pragma unroll
    for (int o = 1; o < 64; o <<= 1) {
        int a = __shfl_up(v, o);
        if (t >= o) v += a;
    }
    if (t < nb) part[t] = v - orig;
    if (t == 63) *off_n = v;
}

__global__ __launch_bounds__(1024) void scan3(
    int* __restrict__ off, int* __restrict__ cur,
    const int* __restrict__ part, int n)
{
    int i = blockIdx.x * 1024 + threadIdx.x;
    if (i < n) {
        int o = off[i] + part[blockIdx.x];
        off[i] = o;
        cur[i] = o;
    }
}

// ---------------------------------------------------------------------------
// CSR fill: slot -> dst (u32). Coalesced over raw edge list.
// ---------------------------------------------------------------------------
__global__ __launch_bounds__(256) void fill_dst(
    const int* __restrict__ ei, int* __restrict__ cur, u32* __restrict__ ccol)
{
    int e = blockIdx.x * 256 + threadIdx.x;
    if (e >= EDGES) return;
    int src = ei[e];
    int dst = ei[EDGES + e];
    int pos = atomicAdd(&cur[src], 1);
    ccol[pos] = (u32)dst;
}

// ---------------------------------------------------------------------------
// CSR-ordered scores: wave per src node. q[src] loaded ONCE (sequential),
// only k[dst] gathered randomly -> halves logical gather volume vs edge order.
// 4 groups of 16 lanes, one edge per group per iteration.
// ---------------------------------------------------------------------------
__global__ __launch_bounds__(256) void score_csr(
    const u16* __restrict__ qb, const u16* __restrict__ kb,
    const int* __restrict__ off, const u32* __restrict__ ccol,
    float* __restrict__ evals, float* __restrict__ nsum, int n)
{
    const int wv   = (blockIdx.x * 256 + threadIdx.x) >> 6;   // src node
    const int lane = threadIdx.x & 63;
    const int l16  = lane & 15;
    const int grp  = lane >> 4;
    if (wv >= n) return;

    const int beg = off[wv];
    const int end = off[wv + 1];

    // q fragment: dims l16*8 .. +7 (identical across the 4 groups)
    uint4 qv = *(const uint4*)(qb + (size_t)wv * HID + l16 * 8);

    #pragma unroll 2
    for (int j = beg; j < end; j += 4) {
        int e = j + grp;
        if (e < end) {
            u32 dst = ccol[e];
            uint4 kv = *(const uint4*)(kb + (size_t)dst * HID + l16 * 8);
            float p = bdot2(qv.x, kv.x) + bdot2(qv.y, kv.y) +
                      bdot2(qv.z, kv.z) + bdot2(qv.w, kv.w);
            p += __shfl_xor(p, 1);
            p += __shfl_xor(p, 2);
            if ((l16 & 3) == 0) {
                int head = l16 >> 2;
                float ev = __expf(p * SCORE_SCALE);
                evals[(size_t)e * HEADS + head] = ev;
                atomicAdd(&nsum[(size_t)dst * HEADS + head], ev);
            }
        }
    }
}

// ---------------------------------------------------------------------------
// head-mean attention; packs epack[pos] = dst | bf16(att)<<16 IN PLACE over
// the dst-only CSR array.
// ---------------------------------------------------------------------------
__global__ __launch_bounds__(256) void finalize_kernel(
    const float* __restrict__ evals, const float* __restrict__ nsum,
    u32* __restrict__ epack)
{
    int pos = blockIdx.x * 256 + threadIdx.x;
    if (pos >= EDGES) return;
    u32 dst = epack[pos];
    float4 ev = *(const float4*)(evals + (size_t)pos * HEADS);
    float4 sv = *(const float4*)(nsum  + (size_t)dst * HEADS);
    float am = 0.25f * (ev.x / (sv.x + 1e-16f) + ev.y / (sv.y + 1e-16f) +
                        ev.z / (sv.z + 1e-16f) + ev.w / (sv.w + 1e-16f));
    epack[pos] = dst | ((u32)f2bf(am) << 16);
}

// ---------------------------------------------------------------------------
// Euler step: out[i,:] = 0.75*in[i,:] + 0.25 * sum_j att[j]*in_bf[dst[j],:]
// Wave per node (full 256B row gathers); 8-deep batched gathers for MLP.
// ---------------------------------------------------------------------------
template<int WRITE_BF>
__global__ __launch_bounds__(256) void spmv_kernel(
    const float* __restrict__ inf, const u16* __restrict__ inb,
    float* __restrict__ outf, u16* __restrict__ outb,
    const int* __restrict__ off, const u32* __restrict__ epack, int n)
{
    const int w    = (blockIdx.x * 256 + threadIdx.x) >> 6;
    const int lane = threadIdx.x & 63;
    if (w >= n) return;

    const int beg = off[w];
    const int end = off[w + 1];

    float ax = 0.f, ay = 0.f;
    for (int j = beg; j < end; j += 64) {
        int cnt = end - j; if (cnt > 64) cnt = 64;
        u32 e = 0;
        if (lane < cnt) e = epack[j + lane];

        int jj = 0;
        for (; jj + 8 <= cnt; jj += 8) {
            u32 ee[8], s[8];
            #pragma unroll
            for (int u = 0; u < 8; ++u) ee[u] = __shfl(e, jj + u);
            #pragma unroll
            for (int u = 0; u < 8; ++u)
                s[u] = *(const u32*)(inb + (size_t)(ee[u] & 0xFFFFu) * HID + lane * 2);
            #pragma unroll
            for (int u = 0; u < 8; ++u) {
                float vv = bfhi(ee[u]);
                ax += vv * bflo(s[u]);
                ay += vv * bfhi(s[u]);
            }
        }
        for (; jj + 4 <= cnt; jj += 4) {
            u32 ee[4], s[4];
            #pragma unroll
            for (int u = 0; u < 4; ++u) ee[u] = __shfl(e, jj + u);
            #pragma unroll
            for (int u = 0; u < 4; ++u)
                s[u] = *(const u32*)(inb + (size_t)(ee[u] & 0xFFFFu) * HID + lane * 2);
            #pragma unroll
            for (int u = 0; u < 4; ++u) {
                float vv = bfhi(ee[u]);
                ax += vv * bflo(s[u]);
                ay += vv * bfhi(s[u]);
            }
        }
        for (; jj < cnt; ++jj) {
            u32 ee = __shfl(e, jj);
            u32 s  = *(const u32*)(inb + (size_t)(ee & 0xFFFFu) * HID + lane * 2);
            float vv = bfhi(ee);
            ax += vv * bflo(s);
            ay += vv * bfhi(s);
        }
    }
    float2 xi = *(const float2*)(inf + (size_t)w * HID + lane * 2);
    float2 o;
    o.x = 0.75f * xi.x + 0.25f * ax;
    o.y = 0.75f * xi.y + 0.25f * ay;
    *(float2*)(outf + (size_t)w * HID + lane * 2) = o;
    if (WRITE_BF) {
        u32 pb = ((u32)f2bf(o.y) << 16) | (u32)f2bf(o.x);
        *(u32*)(outb + (size_t)w * HID + lane * 2) = pb;
    }
}

// ---------------------------------------------------------------------------
extern "C" void kernel_launch(void* const* d_in, const int* in_sizes, int n_in,
                              void* d_out, int out_size, void* d_ws, size_t ws_size,
                              hipStream_t stream)
{
    (void)in_sizes; (void)n_in; (void)out_size; (void)ws_size;

    const float* x  = (const float*)d_in[0];
    const float* Wq = (const float*)d_in[1];
    const float* bq = (const float*)d_in[2];
    const float* Wk = (const float*)d_in[3];
    const float* bk = (const float*)d_in[4];
    const int*   ei = (const int*)d_in[5];
    float* out = (float*)d_out;

    const int N = NODES, E = EDGES;
    const size_t ROWB_B = (size_t)N * HID * 2;   // 12.8 MB bf16 state

    char* ws = (char*)d_ws;
    // region A: qb|kb  -- dead after score -- reused as stA_f
    u16*   qb    = (u16*)(ws);
    u16*   kb    = (u16*)(ws + ROWB_B);
    float* stA_f = (float*)(ws);
    ws += 2 * ROWB_B;
    // region B: xb|evals -- dead after spmv1 / finalize -- reused as stB_f
    u16*   xb    = (u16*)(ws);
    float* evals = (float*)(ws + ROWB_B);
    float* stB_f = (float*)(xb);
    ws += 2 * ROWB_B;
    u16*   stA_b = (u16*)ws;  ws += ROWB_B;
    u16*   stB_b = (u16*)ws;  ws += ROWB_B;
    float* nsum  = (float*)ws; ws += (size_t)N * HEADS * 4;
    int*   deg   = (int*)ws;   ws += (size_t)N * 4;
    int*   off   = (int*)ws;   ws += ((size_t)(N + 1) * 4 + 255) & ~255ull;
    int*   cur   = (int*)ws;   ws += (size_t)N * 4;
    int*   part  = (int*)ws;   ws += 256;
    u32*   epack = (u32*)ws;   ws += (size_t)E * 4;   // dst-only CSR, then packed
    u16*   Wqt   = (u16*)ws;   ws += (size_t)128 * 128 * 2;
    u16*   Wkt   = (u16*)ws;   ws += (size_t)128 * 128 * 2;

    // zero nsum + deg (contiguous)
    hipMemsetAsync(nsum, 0, (size_t)N * HEADS * 4 + (size_t)N * 4, stream);

    // W -> bf16 transposed
    wprep<<<128, 256, 0, stream>>>(Wq, Wk, Wqt, Wkt);

    // Q/K projections via MFMA (bf16 out) + row-major bf16 copy of x
    gemm_qk_mfma<<<(N + 63) / 64, 256, 0, stream>>>(
        x, Wqt, bq, Wkt, bk, qb, kb, xb, N);

    // degree histogram (by src)
    hist_kernel<<<E / 256, 256, 0, stream>>>(ei, deg);

    // CSR offsets: two-level scan
    const int nb = (N + 1023) / 1024;
    scan1<<<nb, 1024, 0, stream>>>(deg, off, part, N);
    scan2<<<1, 64, 0, stream>>>(part, off + N, nb);
    scan3<<<nb, 1024, 0, stream>>>(off, cur, part, N);

    // CSR fill (dst only)
    fill_dst<<<E / 256, 256, 0, stream>>>(ei, cur, epack);

    // CSR-ordered scores -> exp -> segment sums
    score_csr<<<(N * 64 + 255) / 256, 256, 0, stream>>>(
        qb, kb, off, epack, evals, nsum, N);

    // attention mean, packed in place
    finalize_kernel<<<E / 256, 256, 0, stream>>>(evals, nsum, epack);

    // 4 Euler steps
    const int sg = (N * 64 + 255) / 256;
    spmv_kernel<1><<<sg, 256, 0, stream>>>(x,     xb,    stA_f, stA_b, off, epack, N);
    spmv_kernel<1><<<sg, 256, 0, stream>>>(stA_f, stA_b, stB_f, stB_b, off, epack, N);
    spmv_kernel<1><<<sg, 256, 0, stream>>>(stB_f, stB_b, stA_f, stA_b, off, epack, N);
    spmv_kernel<0><<<sg, 256, 0, stream>>>(stA_f, stA_b, out,   nullptr, off, epack, N);
}

// Round 6
// 310.188 us; speedup vs baseline: 1.3869x; 1.0663x over previous
//
#include <hip/hip_runtime.h>

#define NODES 50000
#define EDGES 800000
#define HID   128
#define HEADS 4
// DK = 32, scale = 1/sqrt(32)
#define SCORE_SCALE 0.17677669529663687f

#define NBUCK ((NODES + 255) >> 8)   // 196 buckets of 256 src nodes
#define CHUNK 4096

typedef unsigned int       u32;
typedef unsigned short     u16;
typedef unsigned long long u64;

typedef __attribute__((ext_vector_type(8))) short bf16x8;
typedef __attribute__((ext_vector_type(4))) float f32x4;

// round-to-nearest-even f32 -> bf16
__device__ __forceinline__ u16 f2bf(float f) {
    u32 u = __builtin_bit_cast(u32, f);
    return (u16)((u + 0x7FFFu + ((u >> 16) & 1u)) >> 16);
}
__device__ __forceinline__ float bflo(u32 u) { return __builtin_bit_cast(float, u << 16); }
__device__ __forceinline__ float bfhi(u32 u) { return __builtin_bit_cast(float, u & 0xFFFF0000u); }
__device__ __forceinline__ float bdot2(u32 a, u32 b) {
    return bflo(a) * bflo(b) + bfhi(a) * bfhi(b);
}

// ---------------------------------------------------------------------------
// W prep: Wt[n][k] = bf16(W[k][n]), both 128x128. 2 matrices.
// ---------------------------------------------------------------------------
__global__ __launch_bounds__(256) void wprep(
    const float* __restrict__ Wq, const float* __restrict__ Wk,
    u16* __restrict__ Wqt, u16* __restrict__ Wkt)
{
    int e   = blockIdx.x * 256 + threadIdx.x;
    int mat = e >> 14;
    int idx = e & 16383;
    int k  = idx >> 7;
    int nn = idx & 127;
    const float* W = mat ? Wk : Wq;
    u16*        Wt = mat ? Wkt : Wqt;
    Wt[nn * 128 + k] = f2bf(W[idx]);
}

// ---------------------------------------------------------------------------
// MFMA Q/K projection. Wave = one 16-row tile, both matrices.
// Also emits row-major bf16 copy of x.
// ---------------------------------------------------------------------------
__global__ __launch_bounds__(256) void gemm_qk_mfma(
    const float* __restrict__ x,
    const u16* __restrict__ Wqt, const float* __restrict__ bq,
    const u16* __restrict__ Wkt, const float* __restrict__ bk,
    u16* __restrict__ qb, u16* __restrict__ kb, u16* __restrict__ xb, int n)
{
    const int l  = threadIdx.x & 63;
    const int w  = threadIdx.x >> 6;
    const int lr = l & 15;
    const int kg = l >> 4;

    const int arow   = blockIdx.x * 64 + w * 16 + lr;
    const bool av    = (arow < n);
    const int  arowc = av ? arow : (n - 1);

    bf16x8 afrag[4];
    #pragma unroll
    for (int ks = 0; ks < 4; ++ks) {
        const float* px = x + (size_t)arowc * HID + ks * 32 + kg * 8;
        float4 p0 = *(const float4*)px;
        float4 p1 = *(const float4*)(px + 4);
        uint4 pk;
        pk.x = (u32)f2bf(p0.x) | ((u32)f2bf(p0.y) << 16);
        pk.y = (u32)f2bf(p0.z) | ((u32)f2bf(p0.w) << 16);
        pk.z = (u32)f2bf(p1.x) | ((u32)f2bf(p1.y) << 16);
        pk.w = (u32)f2bf(p1.z) | ((u32)f2bf(p1.w) << 16);
        afrag[ks] = __builtin_bit_cast(bf16x8, pk);
        if (av) *(uint4*)(xb + (size_t)arow * HID + ks * 32 + kg * 8) = pk;
    }

    #pragma unroll
    for (int mat = 0; mat < 2; ++mat) {
        const u16*   Wt   = mat ? Wkt : Wqt;
        const float* bias = mat ? bk : bq;
        u16*         outp = mat ? kb : qb;

        #pragma unroll
        for (int cb = 0; cb < 8; ++cb) {
            float bc = bias[cb * 16 + lr];
            f32x4 acc = {bc, bc, bc, bc};
            #pragma unroll
            for (int ks = 0; ks < 4; ++ks) {
                bf16x8 bfrag = __builtin_bit_cast(bf16x8,
                    *(const uint4*)(Wt + (size_t)(cb * 16 + lr) * 128 + ks * 32 + kg * 8));
                acc = __builtin_amdgcn_mfma_f32_16x16x32_bf16(afrag[ks], bfrag, acc, 0, 0, 0);
            }
            #pragma unroll
            for (int reg = 0; reg < 4; ++reg) {
                int gr = blockIdx.x * 64 + w * 16 + kg * 4 + reg;
                if (gr < n) outp[(size_t)gr * HID + cb * 16 + lr] = f2bf(acc[reg]);
            }
        }
    }
}

// ---------------------------------------------------------------------------
// out-degree histogram over src (separate kernel -- folding it into score
// cost 30us in round 4 via TCC atomic contention)
// ---------------------------------------------------------------------------
__global__ __launch_bounds__(256) void hist_kernel(
    const int* __restrict__ ei, int* __restrict__ deg)
{
    int i = blockIdx.x * 256 + threadIdx.x;
    if (i < EDGES) atomicAdd(&deg[ei[i]], 1);
}

// ---------------------------------------------------------------------------
// two-level exclusive scan of deg -> off; also emits bucket cursors
// ---------------------------------------------------------------------------
__global__ __launch_bounds__(1024) void scan1(
    const int* __restrict__ deg, int* __restrict__ off,
    int* __restrict__ part, int n)
{
    __shared__ int sd[1024];
    int t = threadIdx.x, i = blockIdx.x * 1024 + t;
    int v = (i < n) ? deg[i] : 0;
    sd[t] = v;
    __syncthreads();
    #pragma unroll
    for (int o = 1; o < 1024; o <<= 1) {
        int a = (t >= o) ? sd[t - o] : 0;
        __syncthreads();
        sd[t] += a;
        __syncthreads();
    }
    if (i < n) off[i] = sd[t] - v;
    if (t == 1023) part[blockIdx.x] = sd[1023];
}

__global__ __launch_bounds__(64) void scan2(int* __restrict__ part,
                                            int* __restrict__ off_n, int nb)
{
    int t = threadIdx.x;
    int v = (t < nb) ? part[t] : 0;
    int orig = v;
    #pragma unroll
    for (int o = 1; o < 64; o <<= 1) {
        int a = __shfl_up(v, o);
        if (t >= o) v += a;
    }
    if (t < nb) part[t] = v - orig;
    if (t == 63) *off_n = v;
}

__global__ __launch_bounds__(1024) void scan3(
    int* __restrict__ off, int* __restrict__ bcur,
    const int* __restrict__ part, int n)
{
    int i = blockIdx.x * 1024 + threadIdx.x;
    if (i < n) {
        int o = off[i] + part[blockIdx.x];
        off[i] = o;
        if ((i & 255) == 0) bcur[i >> 8] = o;   // bucket base cursor
    }
}

// ---------------------------------------------------------------------------
// Phase 1: bin edges by bucket (src>>8) into tmp, bucket-contiguous.
// Packed u32: bucket(8b, bits24-31) | srcLocal(8b, bits16-23) | dst(16b).
// Per-block LDS histogram -> one global atomicAdd per touched bucket ->
// contiguous ~21-edge runs per bucket (cheap writes vs 4B global scatter).
// ---------------------------------------------------------------------------
__global__ __launch_bounds__(256) void bin_edges(
    const int* __restrict__ ei, int* __restrict__ bcur, u32* __restrict__ tmp)
{
    __shared__ u32 buf[CHUNK];
    __shared__ int hist[NBUCK];
    __shared__ int lcur[NBUCK];

    const int t  = threadIdx.x;
    const int e0 = blockIdx.x * CHUNK;
    const int e1 = (e0 + CHUNK < EDGES) ? e0 + CHUNK : EDGES;
    const int cnt = e1 - e0;

    for (int b = t; b < NBUCK; b += 256) hist[b] = 0;
    __syncthreads();

    for (int i = t; i < cnt; i += 256) {
        int src = ei[e0 + i];
        int dst = ei[EDGES + e0 + i];
        buf[i] = (u32)dst | ((u32)(src & 255) << 16) | ((u32)(src >> 8) << 24);
        atomicAdd(&hist[src >> 8], 1);
    }
    __syncthreads();

    for (int b = t; b < NBUCK; b += 256) {
        int h = hist[b];
        lcur[b] = h ? atomicAdd(&bcur[b], h) : 0;
    }
    __syncthreads();

    for (int i = t; i < cnt; i += 256) {
        u32 pk  = buf[i];
        int b   = pk >> 24;
        int pos = atomicAdd(&lcur[b], 1);
        tmp[pos] = pk & 0x00FFFFFFu;          // srcLocal<<16 | dst
    }
}

// ---------------------------------------------------------------------------
// Phase 2: exact CSR placement within each bucket. One block per bucket:
// scatter window is 16KB owned by one CU -> L2-coalesced full-line writes;
// cursors live in LDS (fast atomics).
// ---------------------------------------------------------------------------
__global__ __launch_bounds__(256) void place_edges(
    const u32* __restrict__ tmp, const int* __restrict__ off,
    u32* __restrict__ epack, int n)
{
    __shared__ int lcur[256];
    const int t     = threadIdx.x;
    const int nbase = blockIdx.x << 8;
    const int nend  = (nbase + 256 < n) ? nbase + 256 : n;

    if (nbase + t < nend) lcur[t] = off[nbase + t];
    __syncthreads();

    const int s0 = off[nbase];
    const int s1 = off[nend];
    for (int i = s0 + t; i < s1; i += 256) {
        u32 pk    = tmp[i];
        int local = pk >> 16;
        int pos   = atomicAdd(&lcur[local], 1);
        epack[pos] = pk & 0xFFFFu;            // dst only (att packed later)
    }
}

// ---------------------------------------------------------------------------
// CSR-ordered scores: wave per src node. q[src] loaded ONCE (sequential),
// only k[dst] gathered randomly.
// ---------------------------------------------------------------------------
__global__ __launch_bounds__(256) void score_csr(
    const u16* __restrict__ qb, const u16* __restrict__ kb,
    const int* __restrict__ off, const u32* __restrict__ ccol,
    float* __restrict__ evals, float* __restrict__ nsum, int n)
{
    const int wv   = (blockIdx.x * 256 + threadIdx.x) >> 6;   // src node
    const int lane = threadIdx.x & 63;
    const int l16  = lane & 15;
    const int grp  = lane >> 4;
    if (wv >= n) return;

    const int beg = off[wv];
    const int end = off[wv + 1];

    uint4 qv = *(const uint4*)(qb + (size_t)wv * HID + l16 * 8);

    #pragma unroll 2
    for (int j = beg; j < end; j += 4) {
        int e = j + grp;
        if (e < end) {
            u32 dst = ccol[e];
            uint4 kv = *(const uint4*)(kb + (size_t)dst * HID + l16 * 8);
            float p = bdot2(qv.x, kv.x) + bdot2(qv.y, kv.y) +
                      bdot2(qv.z, kv.z) + bdot2(qv.w, kv.w);
            p += __shfl_xor(p, 1);
            p += __shfl_xor(p, 2);
            if ((l16 & 3) == 0) {
                int head = l16 >> 2;
                float ev = __expf(p * SCORE_SCALE);
                evals[(size_t)e * HEADS + head] = ev;
                atomicAdd(&nsum[(size_t)dst * HEADS + head], ev);
            }
        }
    }
}

// ---------------------------------------------------------------------------
// head-mean attention; packs epack[pos] = dst | bf16(att)<<16 IN PLACE.
// ---------------------------------------------------------------------------
__global__ __launch_bounds__(256) void finalize_kernel(
    const float* __restrict__ evals, const float* __restrict__ nsum,
    u32* __restrict__ epack)
{
    int pos = blockIdx.x * 256 + threadIdx.x;
    if (pos >= EDGES) return;
    u32 dst = epack[pos];
    float4 ev = *(const float4*)(evals + (size_t)pos * HEADS);
    float4 sv = *(const float4*)(nsum  + (size_t)dst * HEADS);
    float am = 0.25f * (ev.x / (sv.x + 1e-16f) + ev.y / (sv.y + 1e-16f) +
                        ev.z / (sv.z + 1e-16f) + ev.w / (sv.w + 1e-16f));
    epack[pos] = dst | ((u32)f2bf(am) << 16);
}

// ---------------------------------------------------------------------------
// Euler step: out[i,:] = 0.75*in[i,:] + 0.25 * sum_j att[j]*in_bf[dst[j],:]
// Wave per node (full 256B row gathers); 8-deep batched gathers for MLP.
// ---------------------------------------------------------------------------
template<int WRITE_BF>
__global__ __launch_bounds__(256) void spmv_kernel(
    const float* __restrict__ inf, const u16* __restrict__ inb,
    float* __restrict__ outf, u16* __restrict__ outb,
    const int* __restrict__ off, const u32* __restrict__ epack, int n)
{
    const int w    = (blockIdx.x * 256 + threadIdx.x) >> 6;
    const int lane = threadIdx.x & 63;
    if (w >= n) return;

    const int beg = off[w];
    const int end = off[w + 1];

    float ax = 0.f, ay = 0.f;
    for (int j = beg; j < end; j += 64) {
        int cnt = end - j; if (cnt > 64) cnt = 64;
        u32 e = 0;
        if (lane < cnt) e = epack[j + lane];

        int jj = 0;
        for (; jj + 8 <= cnt; jj += 8) {
            u32 ee[8], s[8];
            #pragma unroll
            for (int u = 0; u < 8; ++u) ee[u] = __shfl(e, jj + u);
            #pragma unroll
            for (int u = 0; u < 8; ++u)
                s[u] = *(const u32*)(inb + (size_t)(ee[u] & 0xFFFFu) * HID + lane * 2);
            #pragma unroll
            for (int u = 0; u < 8; ++u) {
                float vv = bfhi(ee[u]);
                ax += vv * bflo(s[u]);
                ay += vv * bfhi(s[u]);
            }
        }
        for (; jj + 4 <= cnt; jj += 4) {
            u32 ee[4], s[4];
            #pragma unroll
            for (int u = 0; u < 4; ++u) ee[u] = __shfl(e, jj + u);
            #pragma unroll
            for (int u = 0; u < 4; ++u)
                s[u] = *(const u32*)(inb + (size_t)(ee[u] & 0xFFFFu) * HID + lane * 2);
            #pragma unroll
            for (int u = 0; u < 4; ++u) {
                float vv = bfhi(ee[u]);
                ax += vv * bflo(s[u]);
                ay += vv * bfhi(s[u]);
            }
        }
        for (; jj < cnt; ++jj) {
            u32 ee = __shfl(e, jj);
            u32 s  = *(const u32*)(inb + (size_t)(ee & 0xFFFFu) * HID + lane * 2);
            float vv = bfhi(ee);
            ax += vv * bflo(s);
            ay += vv * bfhi(s);
        }
    }
    float2 xi = *(const float2*)(inf + (size_t)w * HID + lane * 2);
    float2 o;
    o.x = 0.75f * xi.x + 0.25f * ax;
    o.y = 0.75f * xi.y + 0.25f * ay;
    *(float2*)(outf + (size_t)w * HID + lane * 2) = o;
    if (WRITE_BF) {
        u32 pb = ((u32)f2bf(o.y) << 16) | (u32)f2bf(o.x);
        *(u32*)(outb + (size_t)w * HID + lane * 2) = pb;
    }
}

// ---------------------------------------------------------------------------
extern "C" void kernel_launch(void* const* d_in, const int* in_sizes, int n_in,
                              void* d_out, int out_size, void* d_ws, size_t ws_size,
                              hipStream_t stream)
{
    (void)in_sizes; (void)n_in; (void)out_size; (void)ws_size;

    const float* x  = (const float*)d_in[0];
    const float* Wq = (const float*)d_in[1];
    const float* bq = (const float*)d_in[2];
    const float* Wk = (const float*)d_in[3];
    const float* bk = (const float*)d_in[4];
    const int*   ei = (const int*)d_in[5];
    float* out = (float*)d_out;

    const int N = NODES, E = EDGES;
    const size_t ROWB_B = (size_t)N * HID * 2;   // 12.8 MB bf16 state

    char* ws = (char*)d_ws;
    // region A: qb|kb  -- dead after score -- reused as stA_f
    u16*   qb    = (u16*)(ws);
    u16*   kb    = (u16*)(ws + ROWB_B);
    float* stA_f = (float*)(ws);
    ws += 2 * ROWB_B;
    // region B: xb|evals -- dead after spmv1 / finalize -- reused as stB_f
    u16*   xb    = (u16*)(ws);
    float* evals = (float*)(ws + ROWB_B);
    float* stB_f = (float*)(xb);
    ws += 2 * ROWB_B;
    u16*   stA_b = (u16*)ws;  ws += ROWB_B;
    u16*   stB_b = (u16*)ws;  ws += ROWB_B;
    float* nsum  = (float*)ws; ws += (size_t)N * HEADS * 4;
    int*   deg   = (int*)ws;   ws += (size_t)N * 4;
    int*   off   = (int*)ws;   ws += ((size_t)(N + 1) * 4 + 255) & ~255ull;
    int*   bcur  = (int*)ws;   ws += ((size_t)NBUCK * 4 + 255) & ~255ull;
    int*   part  = (int*)ws;   ws += 256;
    u32*   epack = (u32*)ws;   ws += (size_t)E * 4;   // dst-only CSR, then packed
    u32*   tmp   = (u32*)ws;   ws += (size_t)E * 4;   // bucket-grouped edges
    u16*   Wqt   = (u16*)ws;   ws += (size_t)128 * 128 * 2;
    u16*   Wkt   = (u16*)ws;   ws += (size_t)128 * 128 * 2;

    // zero nsum + deg (contiguous)
    hipMemsetAsync(nsum, 0, (size_t)N * HEADS * 4 + (size_t)N * 4, stream);

    // W -> bf16 transposed
    wprep<<<128, 256, 0, stream>>>(Wq, Wk, Wqt, Wkt);

    // Q/K projections via MFMA (bf16 out) + row-major bf16 copy of x
    gemm_qk_mfma<<<(N + 63) / 64, 256, 0, stream>>>(
        x, Wqt, bq, Wkt, bk, qb, kb, xb, N);

    // degree histogram (by src)
    hist_kernel<<<E / 256, 256, 0, stream>>>(ei, deg);

    // CSR offsets: two-level scan (+ bucket cursors)
    const int nb = (N + 1023) / 1024;
    scan1<<<nb, 1024, 0, stream>>>(deg, off, part, N);
    scan2<<<1, 64, 0, stream>>>(part, off + N, nb);
    scan3<<<nb, 1024, 0, stream>>>(off, bcur, part, N);

    // two-phase binned CSR fill (replaces the 53us global scatter)
    bin_edges<<<(E + CHUNK - 1) / CHUNK, 256, 0, stream>>>(ei, bcur, tmp);
    place_edges<<<NBUCK, 256, 0, stream>>>(tmp, off, epack, N);

    // CSR-ordered scores -> exp -> segment sums
    score_csr<<<(N * 64 + 255) / 256, 256, 0, stream>>>(
        qb, kb, off, epack, evals, nsum, N);

    // attention mean, packed in place
    finalize_kernel<<<E / 256, 256, 0, stream>>>(evals, nsum, epack);

    // 4 Euler steps
    const int sg = (N * 64 + 255) / 256;
    spmv_kernel<1><<<sg, 256, 0, stream>>>(x,     xb,    stA_f, stA_b, off, epack, N);
    spmv_kernel<1><<<sg, 256, 0, stream>>>(stA_f, stA_b, stB_f, stB_b, off, epack, N);
    spmv_kernel<1><<<sg, 256, 0, stream>>>(stB_f, stB_b, stA_f, stA_b, off, epack, N);
    spmv_kernel<0><<<sg, 256, 0, stream>>>(stA_f, stA_b, out,   nullptr, off, epack, N);
}